// Round 2
// baseline (866.565 us; speedup 1.0000x reference)
//
#include <hip/hip_runtime.h>
#include <hip/hip_bf16.h>

#define RES   512
#define NCH   64            // channels
#define SP    (RES * RES)   // 262144 texels per plane

// ---------------------------------------------------------------------------
// Kernel 1: transpose planes (3, C, R, R) -> (3, R*R, C)  [texel-major]
// LDS-tiled 64(ch) x 64(spatial), coalesced float4 on both sides.
// grid = 3 * (SP/64) = 12288 blocks, 256 threads.
// ---------------------------------------------------------------------------
__global__ __launch_bounds__(256) void transpose_planes(
    const float* __restrict__ in, float* __restrict__ out)
{
    __shared__ float tile[64][65];   // +1 pad: 2-way bank aliasing max (free on CDNA4)

    int b     = blockIdx.x;
    int plane = b >> 12;             // / 4096 tiles per plane
    int s0    = (b & 4095) << 6;     // * 64 spatial base
    const float* src = in  + (size_t)plane * NCH * SP;
    float*       dst = out + (size_t)plane * SP  * NCH;

    int tid = threadIdx.x;
    int r   = tid >> 4;              // 0..15
    int c4  = (tid & 15) << 2;       // 0,4,...,60

    // load: row = channel, col = spatial (coalesced float4 along spatial)
    #pragma unroll
    for (int it = 0; it < 4; ++it) {
        int ch = r + it * 16;
        float4 v = *(const float4*)(src + (size_t)ch * SP + s0 + c4);
        tile[ch][c4 + 0] = v.x;
        tile[ch][c4 + 1] = v.y;
        tile[ch][c4 + 2] = v.z;
        tile[ch][c4 + 3] = v.w;
    }
    __syncthreads();
    // store: row = spatial, col = channel (coalesced float4 along channel)
    #pragma unroll
    for (int it = 0; it < 4; ++it) {
        int s = r + it * 16;
        float4 v;
        v.x = tile[c4 + 0][s];
        v.y = tile[c4 + 1][s];
        v.z = tile[c4 + 2][s];
        v.w = tile[c4 + 3][s];
        *(float4*)(dst + (size_t)(s0 + s) * NCH + c4) = v;
    }
}

// ---------------------------------------------------------------------------
// Kernel 2: gather from texel-major planes (3, R*R, C).
// 16 threads per point; each thread owns 4 channels (float4).
// Every texel access = 16 lanes x float4 = 256 B contiguous, fully utilized.
// ---------------------------------------------------------------------------
__global__ __launch_bounds__(256) void gather_tp(
    const float* __restrict__ pts,
    const float* __restrict__ tp,
    float* __restrict__ out, int npts)
{
    int t  = blockIdx.x * 256 + threadIdx.x;
    int pt = t >> 4;
    if (pt >= npts) return;
    int cg = (t & 15) << 2;          // channel offset 0..60

    float px = pts[3 * (size_t)pt + 0];
    float py = pts[3 * (size_t)pt + 1];
    float pz = pts[3 * (size_t)pt + 2];

    // plane 0: (x,y); plane 1: (x,z); plane 2: (y,z)  [u->W, v->H]
    float us[3] = {px, px, py};
    float vs[3] = {py, pz, pz};

    float4 acc = make_float4(0.f, 0.f, 0.f, 0.f);

    #pragma unroll
    for (int pl = 0; pl < 3; ++pl) {
        float fx = fminf(fmaxf((us[pl] + 1.0f) * 0.5f * 511.0f, 0.0f), 511.0f);
        float fy = fminf(fmaxf((vs[pl] + 1.0f) * 0.5f * 511.0f, 0.0f), 511.0f);
        float x0f = floorf(fx), y0f = floorf(fy);
        int   x0  = (int)x0f,  y0  = (int)y0f;
        float wx  = fx - x0f,  wy  = fy - y0f;
        int   x1  = min(x0 + 1, RES - 1);
        int   y1  = min(y0 + 1, RES - 1);

        const float* base = tp + (size_t)pl * SP * NCH;
        float4 v00 = *(const float4*)(base + ((size_t)(y0 * RES + x0) * NCH) + cg);
        float4 v01 = *(const float4*)(base + ((size_t)(y0 * RES + x1) * NCH) + cg);
        float4 v10 = *(const float4*)(base + ((size_t)(y1 * RES + x0) * NCH) + cg);
        float4 v11 = *(const float4*)(base + ((size_t)(y1 * RES + x1) * NCH) + cg);

        float w00 = (1.0f - wx) * (1.0f - wy);
        float w01 = wx * (1.0f - wy);
        float w10 = (1.0f - wx) * wy;
        float w11 = wx * wy;

        acc.x += w00 * v00.x + w01 * v01.x + w10 * v10.x + w11 * v11.x;
        acc.y += w00 * v00.y + w01 * v01.y + w10 * v10.y + w11 * v11.y;
        acc.z += w00 * v00.z + w01 * v01.z + w10 * v10.z + w11 * v11.z;
        acc.w += w00 * v00.w + w01 * v01.w + w10 * v10.w + w11 * v11.w;
    }

    *(float4*)(out + (size_t)pt * NCH + cg) = acc;
}

// ---------------------------------------------------------------------------
// Fallback: direct gather from original (3, C, R, R) layout (correct, slow).
// One thread per (point, channel). Used only if ws is too small.
// ---------------------------------------------------------------------------
__global__ __launch_bounds__(256) void gather_direct(
    const float* __restrict__ pts,
    const float* __restrict__ planes,
    float* __restrict__ out, int npts)
{
    long t = (long)blockIdx.x * 256 + threadIdx.x;
    int pt = (int)(t >> 6);
    if (pt >= npts) return;
    int ch = (int)(t & 63);

    float px = pts[3 * (size_t)pt + 0];
    float py = pts[3 * (size_t)pt + 1];
    float pz = pts[3 * (size_t)pt + 2];
    float us[3] = {px, px, py};
    float vs[3] = {py, pz, pz};

    float acc = 0.0f;
    #pragma unroll
    for (int pl = 0; pl < 3; ++pl) {
        float fx = fminf(fmaxf((us[pl] + 1.0f) * 0.5f * 511.0f, 0.0f), 511.0f);
        float fy = fminf(fmaxf((vs[pl] + 1.0f) * 0.5f * 511.0f, 0.0f), 511.0f);
        float x0f = floorf(fx), y0f = floorf(fy);
        int   x0  = (int)x0f,  y0  = (int)y0f;
        float wx  = fx - x0f,  wy  = fy - y0f;
        int   x1  = min(x0 + 1, RES - 1);
        int   y1  = min(y0 + 1, RES - 1);

        const float* base = planes + (size_t)pl * NCH * SP + (size_t)ch * SP;
        float v00 = base[y0 * RES + x0];
        float v01 = base[y0 * RES + x1];
        float v10 = base[y1 * RES + x0];
        float v11 = base[y1 * RES + x1];

        acc += v00 * ((1.0f - wx) * (1.0f - wy))
             + v01 * (wx * (1.0f - wy))
             + v10 * ((1.0f - wx) * wy)
             + v11 * (wx * wy);
    }
    out[(size_t)pt * NCH + ch] = acc;
}

extern "C" void kernel_launch(void* const* d_in, const int* in_sizes, int n_in,
                              void* d_out, int out_size, void* d_ws, size_t ws_size,
                              hipStream_t stream)
{
    (void)n_in; (void)out_size;
    const float* pts    = (const float*)d_in[0];
    const float* planes = (const float*)d_in[1];
    float*       out    = (float*)d_out;
    int npts = in_sizes[0] / 3;

    size_t need = (size_t)3 * NCH * SP * sizeof(float);   // ~201 MB
    if (ws_size >= need) {
        transpose_planes<<<3 * (SP / 64), 256, 0, stream>>>(planes, (float*)d_ws);
        long nthr = (long)npts * 16;
        gather_tp<<<(int)((nthr + 255) / 256), 256, 0, stream>>>(
            pts, (const float*)d_ws, out, npts);
    } else {
        long nthr = (long)npts * 64;
        gather_direct<<<(int)((nthr + 255) / 256), 256, 0, stream>>>(
            pts, planes, out, npts);
    }
}